// Round 17
// baseline (487.013 us; speedup 1.0000x reference)
//
#include <hip/hip_runtime.h>
#include <math.h>

#define NB   16
#define NC   256
#define NP   4096
#define NHD  8
#define FD   64
#define HID  512
#define OC3  1536
#define NG   32
#define CPG  8
#define GEPS 1e-5f

typedef __attribute__((ext_vector_type(8))) short bf16x8;
typedef __attribute__((ext_vector_type(4))) float f32x4;

#define MFMA_BF16(a, b, c) __builtin_amdgcn_mfma_f32_16x16x32_bf16(a, b, c, 0, 0, 0)

__device__ __forceinline__ uint bf16_rne(float v) {
    uint u = __float_as_uint(v);
    return (u + 0x7FFFu + ((u >> 16) & 1u)) >> 16;
}
__device__ __forceinline__ void split2(float v, uint& h, uint& l) {
    h = bf16_rne(v);
    l = bf16_rne(v - __uint_as_float(h << 16));
}
__device__ __forceinline__ void gload16(const void* g, void* l) {
    __builtin_amdgcn_global_load_lds(
        (const __attribute__((address_space(1))) void*)g,
        (__attribute__((address_space(3))) void*)l, 16, 0, 0);
}

// ===================== GroupNorm1 stats: one block per (b,g) =====================
__global__ __launch_bounds__(256) void gn_stats_kernel(const float* __restrict__ x,
                                                       float* __restrict__ mu,
                                                       float* __restrict__ rstd) {
    int bg = blockIdx.x;
    const float4* b4 = (const float4*)(x + (size_t)bg * CPG * NP);
    int t = threadIdx.x;
    float s = 0.f, sq = 0.f;
    #pragma unroll
    for (int i = 0; i < 32; ++i) {
        float4 v = b4[t + i * 256];
        s  += v.x + v.y + v.z + v.w;
        sq += v.x*v.x + v.y*v.y + v.z*v.z + v.w*v.w;
    }
    for (int off = 32; off; off >>= 1) { s += __shfl_down(s, off); sq += __shfl_down(sq, off); }
    __shared__ float ss[4], ssq[4];
    int wid = t >> 6, lane = t & 63;
    if (lane == 0) { ss[wid] = s; ssq[wid] = sq; }
    __syncthreads();
    if (t == 0) {
        float S  = ss[0] + ss[1] + ss[2] + ss[3];
        float SQ = ssq[0] + ssq[1] + ssq[2] + ssq[3];
        const float inv = 1.f / (float)(CPG * NP);
        float m = S * inv;
        float var = SQ * inv - m * m;
        mu[bg] = m;
        rstd[bg] = rsqrtf(var + GEPS);
    }
}

// ===================== GN1 -> per (b,c) affine coefs =====================
__global__ void gn1_coefs_kernel(const float* __restrict__ mu, const float* __restrict__ rstd,
                                 const float* __restrict__ w, const float* __restrict__ bias,
                                 float* __restrict__ ac, float* __restrict__ dc) {
    int i = blockIdx.x * 256 + threadIdx.x;
    if (i >= NB * NC) return;
    int b = i / NC, c = i % NC;
    int g = c / CPG;
    float m = mu[b * NG + g], r = rstd[b * NG + g];
    float a = r * w[c];
    ac[i] = a;
    dc[i] = bias[c] - m * a;
}

// ===================== split qkv_w -> bf16 hi/lo ==========
__global__ void wsplit_kernel(const float* __restrict__ w, ushort* __restrict__ wh,
                              ushort* __restrict__ wl) {
    int i = blockIdx.x * 256 + threadIdx.x;    // 98304 float4
    float4 v = ((const float4*)w)[i];
    uint h, l;
    ushort4 hv, lv;
    split2(v.x, h, l); hv.x = (ushort)h; lv.x = (ushort)l;
    split2(v.y, h, l); hv.y = (ushort)h; lv.y = (ushort)l;
    split2(v.z, h, l); hv.z = (ushort)h; lv.z = (ushort)l;
    split2(v.w, h, l); hv.w = (ushort)h; lv.w = (ushort)l;
    ((ushort4*)wh)[i] = hv;
    ((ushort4*)wl)[i] = lv;
}

// ===================== x -> GN1-affine -> transpose [p][c] -> bf16 hi/lo ==========
__global__ __launch_bounds__(256) void xsplit_kernel(const float* __restrict__ x,
                                                     const float* __restrict__ ac,
                                                     const float* __restrict__ dc,
                                                     ushort* __restrict__ xTh,
                                                     ushort* __restrict__ xTl, int b0) {
    int z = blockIdx.z, bglob = b0 + z;
    int p0 = blockIdx.x * 64, c0 = blockIdx.y * 64;
    const float* xb = x + (size_t)bglob * NC * NP;
    __shared__ float T[64][72];
    int t = threadIdx.x;
    #pragma unroll
    for (int j = 0; j < 4; ++j) {
        int idx = t + j * 256;
        int r = idx >> 4, c4 = idx & 15;
        float4 v = *(const float4*)(xb + (size_t)(c0 + r) * NP + p0 + c4 * 4);
        float a = ac[bglob * NC + c0 + r], d = dc[bglob * NC + c0 + r];
        v.x = fmaf(v.x, a, d); v.y = fmaf(v.y, a, d);
        v.z = fmaf(v.z, a, d); v.w = fmaf(v.w, a, d);
        *(float4*)&T[r][c4 * 4] = v;
    }
    __syncthreads();
    int p = t >> 2, cseg = t & 3;           // 4 lanes -> 64 channels of one p-row
    size_t ob = ((size_t)z * NP + p0 + p) * NC + c0 + cseg * 16;
    #pragma unroll
    for (int half = 0; half < 2; ++half) {
        uint4 uh, ul;
        uint* ph = (uint*)&uh; uint* pl = (uint*)&ul;
        #pragma unroll
        for (int i = 0; i < 4; ++i) {
            int c = cseg * 16 + half * 8 + i * 2;
            uint h0, l0, h1, l1;
            split2(T[c][p], h0, l0);
            split2(T[c + 1][p], h1, l1);
            ph[i] = h0 | (h1 << 16);
            pl[i] = l0 | (l1 << 16);
        }
        *(uint4*)(xTh + ob + half * 8) = uh;
        *(uint4*)(xTl + ob + half * 8) = ul;
    }
}

// ===================== fused KV-ctx + Q dispatch, 8 waves ==========
// grid (12 paths, 32 ptiles, CB), block 512. PATH IS FASTEST-VARYING so consecutive
// blocks alternate KV-heads and Q-tiles -> heterogeneous co-residency per CU.
//   path <  8 : KV GEMM + exp + context MFMA for head = path
//   path >= 8 : Q GEMM tile m0=(path-8)*128 + softmax -> qsT
__global__ __launch_bounds__(512, 4) void kvq_kernel(
        const ushort* __restrict__ Wh, const ushort* __restrict__ Wl,
        const ushort* __restrict__ Bhg, const ushort* __restrict__ Blg,
        float* __restrict__ ctxp, float* __restrict__ kspart,
        ushort* __restrict__ qsTh) {
    __shared__ __align__(16) char smem[69632];
    const int z = blockIdx.z;
    const int path = blockIdx.x;
    const int tile = blockIdx.y;
    const int n0 = tile * 128;
    const ushort* Bh = Bhg + (size_t)NP * NC * z;
    const ushort* Bl = Blg + (size_t)NP * NC * z;

    const int t = threadIdx.x;
    const int w = t >> 6, l = t & 63;
    const int wr = w >> 2, wc = w & 3;      // GEMM: 64-row half x 32-col quarter
    const int l15 = l & 15, kb = l >> 4;

    f32x4 acc[4][2];
    #pragma unroll
    for (int i = 0; i < 4; ++i)
        #pragma unroll
        for (int j = 0; j < 2; ++j)
            acc[i][j] = (f32x4){0.f, 0.f, 0.f, 0.f};

    if (path < NHD) {
        // ================= KV + context path =================
        const int h = path;
        ushort* ekh = (ushort*)smem;        // [64][136] each; alias the (dead) staging area
        ushort* ekl = ekh + 64 * 136;
        ushort* vh_ = ekl + 64 * 136;
        ushort* vl_ = vh_ + 64 * 136;

        for (int k0 = 0; k0 < NC; k0 += 32) {
            {
                int idx = t;                // 512 slots = 128 rows x 4 k-subblocks
                int m = idx & 127, s = idx >> 7;
                int grow = 512 + h * 64 + (m & 63) + ((m >> 6) << 9);  // K rows then V rows
                size_t goA = (size_t)grow * NC + k0 + s * 8;
                size_t goB = (size_t)(n0 + m) * NC + k0 + s * 8;
                int lo = idx * 16;
                gload16(Wh + goA, smem + lo);
                gload16(Wl + goA, smem + 8192 + lo);
                gload16(Bh + goB, smem + 16384 + lo);
                gload16(Bl + goB, smem + 24576 + lo);
            }
            __syncthreads();
            bf16x8 ah[4], al[4];
            #pragma unroll
            for (int fi = 0; fi < 4; ++fi) {
                int off = (kb * 128 + wr * 64 + fi * 16 + l15) * 16;
                ah[fi] = *(const bf16x8*)(smem + off);
                al[fi] = *(const bf16x8*)(smem + 8192 + off);
            }
            #pragma unroll
            for (int fj = 0; fj < 2; ++fj) {
                int off = (kb * 128 + wc * 32 + fj * 16 + l15) * 16;
                bf16x8 bh = *(const bf16x8*)(smem + 16384 + off);
                bf16x8 bl = *(const bf16x8*)(smem + 24576 + off);
                #pragma unroll
                for (int fi = 0; fi < 4; ++fi) {
                    acc[fi][fj] = MFMA_BF16(ah[fi], bh, acc[fi][fj]);
                    acc[fi][fj] = MFMA_BF16(al[fi], bh, acc[fi][fj]);
                    acc[fi][fj] = MFMA_BF16(ah[fi], bl, acc[fi][fj]);
                }
            }
            __syncthreads();
        }

        // epilogue: wr==0 waves hold K rows -> exp + ksum partial; wr==1 hold V rows
        #pragma unroll
        for (int fi = 0; fi < 4; ++fi) {
            #pragma unroll
            for (int r = 0; r < 4; ++r) {
                int row = fi * 16 + kb * 4 + r;
                float rs = 0.f;
                #pragma unroll
                for (int fj = 0; fj < 2; ++fj) {
                    float v = acc[fi][fj][r];
                    float e = (wr == 0) ? __expf(v) : v;
                    rs += e;
                    uint hb, lb;
                    split2(e, hb, lb);
                    int P = wc * 32 + fj * 16 + l15;
                    if (wr == 0) { ekh[row * 136 + P] = (ushort)hb; ekl[row * 136 + P] = (ushort)lb; }
                    else         { vh_[row * 136 + P] = (ushort)hb; vl_[row * 136 + P] = (ushort)lb; }
                }
                if (wr == 0) {
                    rs += __shfl_xor(rs, 1); rs += __shfl_xor(rs, 2);
                    rs += __shfl_xor(rs, 4); rs += __shfl_xor(rs, 8);
                    if (l15 == 0)
                        kspart[((size_t)z * HID + h * 64 + row) * 128 + tile * 4 + wc] = rs;
                }
            }
        }
        __syncthreads();

        // ctx: 64x64 over k=128; wave w computes rows (w>>2)*32 + i*16 (i<2), cols (w&3)*16
        f32x4 c2[2];
        c2[0] = (f32x4){0.f, 0.f, 0.f, 0.f};
        c2[1] = (f32x4){0.f, 0.f, 0.f, 0.f};
        const int cr0 = (w >> 2) * 32;
        const int cc0 = (w & 3) * 16;
        #pragma unroll
        for (int ks = 0; ks < 4; ++ks) {
            bf16x8 a_h[2], a_l[2];
            #pragma unroll
            for (int i = 0; i < 2; ++i) {
                int offa = (cr0 + i * 16 + l15) * 136 + ks * 32 + kb * 8;
                a_h[i] = *(const bf16x8*)(ekh + offa);
                a_l[i] = *(const bf16x8*)(ekl + offa);
            }
            int offb = (cc0 + l15) * 136 + ks * 32 + kb * 8;
            bf16x8 b_h = *(const bf16x8*)(vh_ + offb);
            bf16x8 b_l = *(const bf16x8*)(vl_ + offb);
            #pragma unroll
            for (int i = 0; i < 2; ++i) {
                c2[i] = MFMA_BF16(a_h[i], b_h, c2[i]);
                c2[i] = MFMA_BF16(a_l[i], b_h, c2[i]);
                c2[i] = MFMA_BF16(a_h[i], b_l, c2[i]);
            }
        }
        float* outp = ctxp + (((size_t)z * NHD + h) * 32 + tile) * 4096;
        #pragma unroll
        for (int i = 0; i < 2; ++i)
            #pragma unroll
            for (int r = 0; r < 4; ++r)
                outp[(size_t)(cr0 + i * 16 + kb * 4 + r) * 64 + cc0 + l15] = c2[i][r];
    } else {
        // ================= Q path (8-wave): m0 = (path-8)*128 =================
        const int m0 = (path - NHD) * 128;

        for (int k0 = 0; k0 < NC; k0 += 32) {
            {
                int idx = t;
                int m = idx & 127, s = idx >> 7;
                size_t goA = (size_t)(m0 + m) * NC + k0 + s * 8;
                size_t goB = (size_t)(n0 + m) * NC + k0 + s * 8;
                int lo = idx * 16;
                gload16(Wh + goA, smem + lo);
                gload16(Wl + goA, smem + 8192 + lo);
                gload16(Bh + goB, smem + 16384 + lo);
                gload16(Bl + goB, smem + 24576 + lo);
            }
            __syncthreads();
            bf16x8 ah[4], al[4];
            #pragma unroll
            for (int fi = 0; fi < 4; ++fi) {
                int off = (kb * 128 + wr * 64 + fi * 16 + l15) * 16;
                ah[fi] = *(const bf16x8*)(smem + off);
                al[fi] = *(const bf16x8*)(smem + 8192 + off);
            }
            #pragma unroll
            for (int fj = 0; fj < 2; ++fj) {
                int off = (kb * 128 + wc * 32 + fj * 16 + l15) * 16;
                bf16x8 bh = *(const bf16x8*)(smem + 16384 + off);
                bf16x8 bl = *(const bf16x8*)(smem + 24576 + off);
                #pragma unroll
                for (int fi = 0; fi < 4; ++fi) {
                    acc[fi][fj] = MFMA_BF16(ah[fi], bh, acc[fi][fj]);
                    acc[fi][fj] = MFMA_BF16(al[fi], bh, acc[fi][fj]);
                    acc[fi][fj] = MFMA_BF16(ah[fi], bl, acc[fi][fj]);
                }
            }
            __syncthreads();
        }

        // per-head feature softmax: wave-half wr covers one head (rows wr*64 + fi*16 + kb*4 + r)
        uint* Tq = (uint*)smem;    // [128 p][136], value = hb<<16 (aliases dead staging)
        #pragma unroll
        for (int fj = 0; fj < 2; ++fj) {
            float ex[16];
            float cs = 0.f;
            #pragma unroll
            for (int fi = 0; fi < 4; ++fi)
                #pragma unroll
                for (int r = 0; r < 4; ++r) {
                    float e = __expf(acc[fi][fj][r]);
                    ex[fi * 4 + r] = e;
                    cs += e;
                }
            cs += __shfl_xor(cs, 16);
            cs += __shfl_xor(cs, 32);
            float inv = 0.125f / cs;
            int p_loc = wc * 32 + fj * 16 + l15;
            #pragma unroll
            for (int fi = 0; fi < 4; ++fi)
                #pragma unroll
                for (int r = 0; r < 4; ++r) {
                    uint hb = bf16_rne(ex[fi * 4 + r] * inv);
                    Tq[p_loc * 136 + wr * 64 + fi * 16 + kb * 4 + r] = hb << 16;
                }
        }
        __syncthreads();
        int p = t >> 2, seg = t & 3;        // 128 p-rows x 4 segs of 32 hid
        size_t ob = ((size_t)z * NP + n0 + p) * HID + m0 + seg * 32;
        #pragma unroll
        for (int c = 0; c < 4; ++c) {
            uint4 H;
            uint* hp = (uint*)&H;
            #pragma unroll
            for (int i = 0; i < 4; ++i) {
                uint u0 = Tq[p * 136 + seg * 32 + c * 8 + 2 * i];
                uint u1 = Tq[p * 136 + seg * 32 + c * 8 + 2 * i + 1];
                hp[i] = (u0 >> 16) | (u1 & 0xffff0000u);
            }
            *(uint4*)(qsTh + ob + c * 8) = H;
        }
    }
}

// ===================== ksum reduce: 128 partials per (z,row) ==========
__global__ void ksum_reduce_kernel(const float* __restrict__ kspart,
                                   float* __restrict__ ksum, int n) {
    int i = blockIdx.x * 256 + threadIdx.x;
    if (i >= n) return;
    float s = 0.f;
    #pragma unroll
    for (int j = 0; j < 128; ++j) s += kspart[(size_t)i * 128 + j];
    ksum[i] = s;
}

// ===================== fold (+ctx reduce over 32 partials) ==========
__global__ __launch_bounds__(256) void fold_kernel(const float* __restrict__ out_w,
                                                   const float* __restrict__ ctxp,
                                                   const float* __restrict__ ksum,
                                                   ushort* __restrict__ w2h,
                                                   ushort* __restrict__ w2l) {
    int h = blockIdx.x, z = blockIdx.y;
    __shared__ float Cs[FD][FD];
    int t = threadIdx.x;
    const float* pbase = ctxp + ((size_t)z * NHD + h) * 32 * 4096;
    #pragma unroll
    for (int j = 0; j < 16; ++j) {
        int idx = t + j * 256;
        float s = 0.f;
        #pragma unroll
        for (int p8 = 0; p8 < 32; ++p8) s += pbase[(size_t)p8 * 4096 + idx];
        ((float*)Cs)[idx] = s;
    }
    __syncthreads();
    float wr[64];
    const float* wrow = out_w + (size_t)t * HID + h * FD;
    #pragma unroll
    for (int e = 0; e < 64; ++e) wr[e] = wrow[e];
    size_t ob = ((size_t)z * NC + t) * HID + h * FD;
    for (int f = 0; f < 64; ++f) {
        float sacc = 0.f;
        #pragma unroll
        for (int e = 0; e < 64; ++e) sacc = fmaf(wr[e], Cs[f][e], sacc);
        float v = sacc / ksum[(size_t)z * HID + h * FD + f];
        uint hb, lb;
        split2(v, hb, lb);
        w2h[ob + f] = (ushort)hb;
        w2l[ob + f] = (ushort)lb;
    }
}

// ===================== out GEMM (B = qsT hi-only) + bias + GN2 stats partials ==========
// grid (32, 2, CB), block 256
__global__ __launch_bounds__(256) void gemm_out_kernel(
        const ushort* __restrict__ Ahg, const ushort* __restrict__ Alg,
        const ushort* __restrict__ Bhg,
        const float* __restrict__ bias, float* __restrict__ outg,
        float2* __restrict__ gn2part, int b0) {
    __shared__ __align__(16) char smem[24576];
    const int z = blockIdx.z, bglob = b0 + z;
    const ushort* Ah = Ahg + (size_t)NC * HID * z;
    const ushort* Al = Alg + (size_t)NC * HID * z;
    const ushort* Bh = Bhg + (size_t)NP * HID * z;
    float* C = outg + (size_t)bglob * NC * NP;

    const int t = threadIdx.x;
    const int w = t >> 6, l = t & 63;
    const int wr = w >> 1, wc = w & 1;
    const int m0 = blockIdx.y * 128, n0 = blockIdx.x * 128;
    const int l15 = l & 15, kb = l >> 4;

    f32x4 acc[4][4];
    #pragma unroll
    for (int i = 0; i < 4; ++i)
        #pragma unroll
        for (int j = 0; j < 4; ++j)
            acc[i][j] = (f32x4){0.f, 0.f, 0.f, 0.f};

    for (int k0 = 0; k0 < HID; k0 += 32) {
        #pragma unroll
        for (int j = 0; j < 2; ++j) {
            int idx = t + j * 256;
            int m = idx & 127, s = idx >> 7;
            size_t goA = (size_t)(m0 + m) * HID + k0 + s * 8;
            size_t goB = (size_t)(n0 + m) * HID + k0 + s * 8;
            int lo = idx * 16;
            gload16(Ah + goA, smem + lo);
            gload16(Al + goA, smem + 8192 + lo);
            gload16(Bh + goB, smem + 16384 + lo);
        }
        __syncthreads();
        bf16x8 ah[4], al[4];
        #pragma unroll
        for (int fi = 0; fi < 4; ++fi) {
            int off = (kb * 128 + wr * 64 + fi * 16 + l15) * 16;
            ah[fi] = *(const bf16x8*)(smem + off);
            al[fi] = *(const bf16x8*)(smem + 8192 + off);
        }
        #pragma unroll
        for (int fj = 0; fj < 4; ++fj) {
            int off = (kb * 128 + wc * 64 + fj * 16 + l15) * 16;
            bf16x8 bh = *(const bf16x8*)(smem + 16384 + off);
            #pragma unroll
            for (int fi = 0; fi < 4; ++fi) {
                acc[fi][fj] = MFMA_BF16(ah[fi], bh, acc[fi][fj]);
                acc[fi][fj] = MFMA_BF16(al[fi], bh, acc[fi][fj]);
            }
        }
        __syncthreads();
    }

    float gs[4] = {0.f, 0.f, 0.f, 0.f}, gq[4] = {0.f, 0.f, 0.f, 0.f};
    #pragma unroll
    for (int fi = 0; fi < 4; ++fi) {
        int mbase = m0 + wr * 64 + fi * 16 + kb * 4;
        #pragma unroll
        for (int fj = 0; fj < 4; ++fj) {
            int n = n0 + wc * 64 + fj * 16 + l15;
            #pragma unroll
            for (int r = 0; r < 4; ++r) {
                float v = acc[fi][fj][r] + bias[mbase + r];
                C[(size_t)(mbase + r) * NP + n] = v;
                gs[fi] += v;
                gq[fi] += v * v;
            }
        }
    }
    #pragma unroll
    for (int fi = 0; fi < 4; ++fi) {
        #pragma unroll
        for (int d = 1; d <= 16; d <<= 1) {
            gs[fi] += __shfl_xor(gs[fi], d);
            gq[fi] += __shfl_xor(gq[fi], d);
        }
    }
    if (l15 == 0 && (kb & 1) == 0) {
        #pragma unroll
        for (int fi = 0; fi < 4; ++fi) {
            int g = ((m0 + wr * 64) >> 3) + fi * 2 + (kb >> 1);
            float2 pv; pv.x = gs[fi]; pv.y = gq[fi];
            gn2part[(((size_t)bglob * NG + g) << 6) + blockIdx.x * 2 + wc] = pv;
        }
    }
}

// ===================== GN2 partial reduce -> mu/rstd ==========
__global__ void gn2_reduce_kernel(const float2* __restrict__ gn2part,
                                  float* __restrict__ mu, float* __restrict__ rstd) {
    int i = blockIdx.x * 256 + threadIdx.x;   // NB*NG = 512
    if (i >= NB * NG) return;
    float s = 0.f, q = 0.f;
    #pragma unroll
    for (int j = 0; j < 64; ++j) {
        float2 p = gn2part[((size_t)i << 6) + j];
        s += p.x; q += p.y;
    }
    const float inv = 1.f / (float)(CPG * NP);
    float m = s * inv;
    float var = q * inv - m * m;
    mu[i] = m;
    rstd[i] = rsqrtf(var + GEPS);
}

// ===================== GN2 apply in-place on d_out =====================
__global__ void gn2_apply_kernel(float* __restrict__ out, const float* __restrict__ mu,
                                 const float* __restrict__ rstd, const float* __restrict__ w,
                                 const float* __restrict__ bias) {
    int i = blockIdx.x * 256 + threadIdx.x;
    float4* p = (float4*)out;
    float4 v = p[i];
    size_t e0 = (size_t)i * 4;
    int cidx = (int)((e0 / NP) % NC);
    int bg   = (int)(e0 / ((size_t)CPG * NP));
    float m = mu[bg], r = rstd[bg];
    float a = r * w[cidx];
    float d = bias[cidx] - m * a;
    v.x = fmaf(v.x, a, d); v.y = fmaf(v.y, a, d);
    v.z = fmaf(v.z, a, d); v.w = fmaf(v.w, a, d);
    p[i] = v;
}

// ===================== launch =====================
extern "C" void kernel_launch(void* const* d_in, const int* in_sizes, int n_in,
                              void* d_out, int out_size, void* d_ws, size_t ws_size,
                              hipStream_t stream) {
    const float* x     = (const float*)d_in[0];
    const float* gn1_w = (const float*)d_in[1];
    const float* gn1_b = (const float*)d_in[2];
    const float* qkv_w = (const float*)d_in[3];
    const float* out_w = (const float*)d_in[4];
    const float* out_b = (const float*)d_in[5];
    const float* gn2_w = (const float*)d_in[6];
    const float* gn2_b = (const float*)d_in[7];
    float* out = (float*)d_out;

    // ---- pick chunk size CB by workspace budget ----
    auto need = [](int cb) -> size_t {
        size_t tot = 0;
        auto al = [&](size_t b) { tot = (tot + b + 255) & ~(size_t)255; };
        al((size_t)cb * NP * NC * 2);  al((size_t)cb * NP * NC * 2);   // xT h/l
        al((size_t)cb * NP * HID * 2);                                 // qsT (hi only)
        al((size_t)cb * NHD * 32 * FD * FD * 4);                       // ctxp (32 tile partials)
        al((size_t)cb * HID * 128 * 4);                                // kspart
        al((size_t)cb * HID * 4);                                      // ksum
        al((size_t)cb * NC * HID * 2); al((size_t)cb * NC * HID * 2);  // w2 h/l
        al((size_t)OC3 * NC * 2); al((size_t)OC3 * NC * 2);            // Wq h/l
        al((size_t)2 * NB * NC * 4);                                   // ac,dc
        al((size_t)4 * NB * NG * 4);                                   // gn1/gn2 stats
        al((size_t)NB * NG * 64 * 8);                                  // gn2part float2
        return tot;
    };
    int CB = 1;
    {
        const int cands[5] = {16, 8, 4, 2, 1};
        for (int i = 0; i < 5; ++i) if (need(cands[i]) <= ws_size) { CB = cands[i]; break; }
    }

    // ---- carve workspace (same order as need()) ----
    char* base = (char*)d_ws;
    size_t off = 0;
    auto carve = [&](size_t b) -> char* {
        char* p = base + off;
        off = (off + b + 255) & ~(size_t)255;
        return p;
    };
    ushort* xTh  = (ushort*)carve((size_t)CB * NP * NC * 2);
    ushort* xTl  = (ushort*)carve((size_t)CB * NP * NC * 2);
    ushort* qsTh = (ushort*)carve((size_t)CB * NP * HID * 2);
    float*  ctxp = (float*) carve((size_t)CB * NHD * 32 * FD * FD * 4);
    float*  kspart = (float*)carve((size_t)CB * HID * 128 * 4);
    float*  ksum = (float*) carve((size_t)CB * HID * 4);
    ushort* w2h  = (ushort*)carve((size_t)CB * NC * HID * 2);
    ushort* w2l  = (ushort*)carve((size_t)CB * NC * HID * 2);
    ushort* Wqh  = (ushort*)carve((size_t)OC3 * NC * 2);
    ushort* Wql  = (ushort*)carve((size_t)OC3 * NC * 2);
    float*  ac   = (float*) carve((size_t)2 * NB * NC * 4);
    float*  dc   = ac + (size_t)NB * NC;
    float*  mu1  = (float*) carve((size_t)4 * NB * NG * 4);
    float*  rstd1 = mu1 + NB * NG;
    float*  mu2   = rstd1 + NB * NG;
    float*  rstd2 = mu2 + NB * NG;
    float2* gn2part = (float2*)carve((size_t)NB * NG * 64 * 8);

    // 1. GN1 stats + affine coefs + weight split
    gn_stats_kernel<<<NB * NG, 256, 0, stream>>>(x, mu1, rstd1);
    gn1_coefs_kernel<<<16, 256, 0, stream>>>(mu1, rstd1, gn1_w, gn1_b, ac, dc);
    wsplit_kernel<<<OC3 * NC / 1024, 256, 0, stream>>>(qkv_w, Wqh, Wql);

    // 2. chunked pipeline (KV-ctx and Q interleaved in one dispatch, path fastest-varying)
    for (int b0 = 0; b0 < NB; b0 += CB) {
        xsplit_kernel<<<dim3(NP / 64, NC / 64, CB), 256, 0, stream>>>(x, ac, dc, xTh, xTl, b0);
        kvq_kernel<<<dim3(NHD + 4, NP / 128, CB), 512, 0, stream>>>(
            Wqh, Wql, xTh, xTl, ctxp, kspart, qsTh);
        ksum_reduce_kernel<<<(CB * HID + 255) / 256, 256, 0, stream>>>(kspart, ksum, CB * HID);
        fold_kernel<<<dim3(NHD, CB), 256, 0, stream>>>(out_w, ctxp, ksum, w2h, w2l);
        gemm_out_kernel<<<dim3(NP / 128, 2, CB), 256, 0, stream>>>(
            w2h, w2l, qsTh, out_b, out, gn2part, b0);
    }

    // 3. GN2 finalize
    gn2_reduce_kernel<<<2, 256, 0, stream>>>(gn2part, mu2, rstd2);
    gn2_apply_kernel<<<16384, 256, 0, stream>>>(out, mu2, rstd2, gn2_w, gn2_b);
}

// Round 18
// 472.885 us; speedup vs baseline: 1.0299x; 1.0299x over previous
//
#include <hip/hip_runtime.h>
#include <math.h>

#define NB   16
#define NC   256
#define NP   4096
#define NHD  8
#define FD   64
#define HID  512
#define OC3  1536
#define NG   32
#define CPG  8
#define GEPS 1e-5f

typedef __attribute__((ext_vector_type(8))) short bf16x8;
typedef __attribute__((ext_vector_type(4))) float f32x4;

#define MFMA_BF16(a, b, c) __builtin_amdgcn_mfma_f32_16x16x32_bf16(a, b, c, 0, 0, 0)

__device__ __forceinline__ uint bf16_rne(float v) {
    uint u = __float_as_uint(v);
    return (u + 0x7FFFu + ((u >> 16) & 1u)) >> 16;
}
__device__ __forceinline__ void split2(float v, uint& h, uint& l) {
    h = bf16_rne(v);
    l = bf16_rne(v - __uint_as_float(h << 16));
}
__device__ __forceinline__ void gload16(const void* g, void* l) {
    __builtin_amdgcn_global_load_lds(
        (const __attribute__((address_space(1))) void*)g,
        (__attribute__((address_space(3))) void*)l, 16, 0, 0);
}

// ===================== GroupNorm1 stats: one block per (b,g) =====================
__global__ __launch_bounds__(256) void gn_stats_kernel(const float* __restrict__ x,
                                                       float* __restrict__ mu,
                                                       float* __restrict__ rstd) {
    int bg = blockIdx.x;
    const float4* b4 = (const float4*)(x + (size_t)bg * CPG * NP);
    int t = threadIdx.x;
    float s = 0.f, sq = 0.f;
    #pragma unroll
    for (int i = 0; i < 32; ++i) {
        float4 v = b4[t + i * 256];
        s  += v.x + v.y + v.z + v.w;
        sq += v.x*v.x + v.y*v.y + v.z*v.z + v.w*v.w;
    }
    for (int off = 32; off; off >>= 1) { s += __shfl_down(s, off); sq += __shfl_down(sq, off); }
    __shared__ float ss[4], ssq[4];
    int wid = t >> 6, lane = t & 63;
    if (lane == 0) { ss[wid] = s; ssq[wid] = sq; }
    __syncthreads();
    if (t == 0) {
        float S  = ss[0] + ss[1] + ss[2] + ss[3];
        float SQ = ssq[0] + ssq[1] + ssq[2] + ssq[3];
        const float inv = 1.f / (float)(CPG * NP);
        float m = S * inv;
        float var = SQ * inv - m * m;
        mu[bg] = m;
        rstd[bg] = rsqrtf(var + GEPS);
    }
}

// ===================== GN1 -> per (b,c) affine coefs =====================
__global__ void gn1_coefs_kernel(const float* __restrict__ mu, const float* __restrict__ rstd,
                                 const float* __restrict__ w, const float* __restrict__ bias,
                                 float* __restrict__ ac, float* __restrict__ dc) {
    int i = blockIdx.x * 256 + threadIdx.x;
    if (i >= NB * NC) return;
    int b = i / NC, c = i % NC;
    int g = c / CPG;
    float m = mu[b * NG + g], r = rstd[b * NG + g];
    float a = r * w[c];
    ac[i] = a;
    dc[i] = bias[c] - m * a;
}

// ===================== split qkv_w -> bf16 hi/lo ==========
__global__ void wsplit_kernel(const float* __restrict__ w, ushort* __restrict__ wh,
                              ushort* __restrict__ wl) {
    int i = blockIdx.x * 256 + threadIdx.x;    // 98304 float4
    float4 v = ((const float4*)w)[i];
    uint h, l;
    ushort4 hv, lv;
    split2(v.x, h, l); hv.x = (ushort)h; lv.x = (ushort)l;
    split2(v.y, h, l); hv.y = (ushort)h; lv.y = (ushort)l;
    split2(v.z, h, l); hv.z = (ushort)h; lv.z = (ushort)l;
    split2(v.w, h, l); hv.w = (ushort)h; lv.w = (ushort)l;
    ((ushort4*)wh)[i] = hv;
    ((ushort4*)wl)[i] = lv;
}

// ===================== x -> GN1-affine -> transpose [p][c] -> bf16 hi/lo ==========
__global__ __launch_bounds__(256) void xsplit_kernel(const float* __restrict__ x,
                                                     const float* __restrict__ ac,
                                                     const float* __restrict__ dc,
                                                     ushort* __restrict__ xTh,
                                                     ushort* __restrict__ xTl, int b0) {
    int z = blockIdx.z, bglob = b0 + z;
    int p0 = blockIdx.x * 64, c0 = blockIdx.y * 64;
    const float* xb = x + (size_t)bglob * NC * NP;
    __shared__ float T[64][72];
    int t = threadIdx.x;
    #pragma unroll
    for (int j = 0; j < 4; ++j) {
        int idx = t + j * 256;
        int r = idx >> 4, c4 = idx & 15;
        float4 v = *(const float4*)(xb + (size_t)(c0 + r) * NP + p0 + c4 * 4);
        float a = ac[bglob * NC + c0 + r], d = dc[bglob * NC + c0 + r];
        v.x = fmaf(v.x, a, d); v.y = fmaf(v.y, a, d);
        v.z = fmaf(v.z, a, d); v.w = fmaf(v.w, a, d);
        *(float4*)&T[r][c4 * 4] = v;
    }
    __syncthreads();
    int p = t >> 2, cseg = t & 3;           // 4 lanes -> 64 channels of one p-row
    size_t ob = ((size_t)z * NP + p0 + p) * NC + c0 + cseg * 16;
    #pragma unroll
    for (int half = 0; half < 2; ++half) {
        uint4 uh, ul;
        uint* ph = (uint*)&uh; uint* pl = (uint*)&ul;
        #pragma unroll
        for (int i = 0; i < 4; ++i) {
            int c = cseg * 16 + half * 8 + i * 2;
            uint h0, l0, h1, l1;
            split2(T[c][p], h0, l0);
            split2(T[c + 1][p], h1, l1);
            ph[i] = h0 | (h1 << 16);
            pl[i] = l0 | (l1 << 16);
        }
        *(uint4*)(xTh + ob + half * 8) = uh;
        *(uint4*)(xTl + ob + half * 8) = ul;
    }
}

// ===================== fused KV-ctx + Q dispatch, 8 waves ==========
// grid (32 ptiles, 12, CB), block 512.
//   blockIdx.y <  8 : KV GEMM + exp + context MFMA for head y
//   blockIdx.y >= 8 : Q GEMM tile m0=(y-8)*128 + softmax -> qsT
__global__ __launch_bounds__(512, 4) void kvq_kernel(
        const ushort* __restrict__ Wh, const ushort* __restrict__ Wl,
        const ushort* __restrict__ Bhg, const ushort* __restrict__ Blg,
        float* __restrict__ ctxp, float* __restrict__ kspart,
        ushort* __restrict__ qsTh) {
    __shared__ __align__(16) char smem[69632];
    const int z = blockIdx.z;
    const int tile = blockIdx.x;
    const int n0 = tile * 128;
    const ushort* Bh = Bhg + (size_t)NP * NC * z;
    const ushort* Bl = Blg + (size_t)NP * NC * z;

    const int t = threadIdx.x;
    const int w = t >> 6, l = t & 63;
    const int wr = w >> 2, wc = w & 3;      // GEMM: 64-row half x 32-col quarter
    const int l15 = l & 15, kb = l >> 4;

    f32x4 acc[4][2];
    #pragma unroll
    for (int i = 0; i < 4; ++i)
        #pragma unroll
        for (int j = 0; j < 2; ++j)
            acc[i][j] = (f32x4){0.f, 0.f, 0.f, 0.f};

    if (blockIdx.y < NHD) {
        // ================= KV + context path =================
        const int h = blockIdx.y;
        ushort* ekh = (ushort*)smem;        // [64][136] each; alias the (dead) staging area
        ushort* ekl = ekh + 64 * 136;
        ushort* vh_ = ekl + 64 * 136;
        ushort* vl_ = vh_ + 64 * 136;

        for (int k0 = 0; k0 < NC; k0 += 32) {
            {
                int idx = t;                // 512 slots = 128 rows x 4 k-subblocks
                int m = idx & 127, s = idx >> 7;
                int grow = 512 + h * 64 + (m & 63) + ((m >> 6) << 9);  // K rows then V rows
                size_t goA = (size_t)grow * NC + k0 + s * 8;
                size_t goB = (size_t)(n0 + m) * NC + k0 + s * 8;
                int lo = idx * 16;
                gload16(Wh + goA, smem + lo);
                gload16(Wl + goA, smem + 8192 + lo);
                gload16(Bh + goB, smem + 16384 + lo);
                gload16(Bl + goB, smem + 24576 + lo);
            }
            __syncthreads();
            bf16x8 ah[4], al[4];
            #pragma unroll
            for (int fi = 0; fi < 4; ++fi) {
                int off = (kb * 128 + wr * 64 + fi * 16 + l15) * 16;
                ah[fi] = *(const bf16x8*)(smem + off);
                al[fi] = *(const bf16x8*)(smem + 8192 + off);
            }
            #pragma unroll
            for (int fj = 0; fj < 2; ++fj) {
                int off = (kb * 128 + wc * 32 + fj * 16 + l15) * 16;
                bf16x8 bh = *(const bf16x8*)(smem + 16384 + off);
                bf16x8 bl = *(const bf16x8*)(smem + 24576 + off);
                #pragma unroll
                for (int fi = 0; fi < 4; ++fi) {
                    acc[fi][fj] = MFMA_BF16(ah[fi], bh, acc[fi][fj]);
                    acc[fi][fj] = MFMA_BF16(al[fi], bh, acc[fi][fj]);
                    acc[fi][fj] = MFMA_BF16(ah[fi], bl, acc[fi][fj]);
                }
            }
            __syncthreads();
        }

        // epilogue: wr==0 waves hold K rows -> exp + ksum partial; wr==1 hold V rows
        #pragma unroll
        for (int fi = 0; fi < 4; ++fi) {
            #pragma unroll
            for (int r = 0; r < 4; ++r) {
                int row = fi * 16 + kb * 4 + r;
                float rs = 0.f;
                #pragma unroll
                for (int fj = 0; fj < 2; ++fj) {
                    float v = acc[fi][fj][r];
                    float e = (wr == 0) ? __expf(v) : v;
                    rs += e;
                    uint hb, lb;
                    split2(e, hb, lb);
                    int P = wc * 32 + fj * 16 + l15;
                    if (wr == 0) { ekh[row * 136 + P] = (ushort)hb; ekl[row * 136 + P] = (ushort)lb; }
                    else         { vh_[row * 136 + P] = (ushort)hb; vl_[row * 136 + P] = (ushort)lb; }
                }
                if (wr == 0) {
                    rs += __shfl_xor(rs, 1); rs += __shfl_xor(rs, 2);
                    rs += __shfl_xor(rs, 4); rs += __shfl_xor(rs, 8);
                    if (l15 == 0)
                        kspart[((size_t)z * HID + h * 64 + row) * 128 + tile * 4 + wc] = rs;
                }
            }
        }
        __syncthreads();

        // ctx: 64x64 over k=128; wave w computes rows (w>>2)*32 + i*16 (i<2), cols (w&3)*16
        f32x4 c2[2];
        c2[0] = (f32x4){0.f, 0.f, 0.f, 0.f};
        c2[1] = (f32x4){0.f, 0.f, 0.f, 0.f};
        const int cr0 = (w >> 2) * 32;
        const int cc0 = (w & 3) * 16;
        #pragma unroll
        for (int ks = 0; ks < 4; ++ks) {
            bf16x8 a_h[2], a_l[2];
            #pragma unroll
            for (int i = 0; i < 2; ++i) {
                int offa = (cr0 + i * 16 + l15) * 136 + ks * 32 + kb * 8;
                a_h[i] = *(const bf16x8*)(ekh + offa);
                a_l[i] = *(const bf16x8*)(ekl + offa);
            }
            int offb = (cc0 + l15) * 136 + ks * 32 + kb * 8;
            bf16x8 b_h = *(const bf16x8*)(vh_ + offb);
            bf16x8 b_l = *(const bf16x8*)(vl_ + offb);
            #pragma unroll
            for (int i = 0; i < 2; ++i) {
                c2[i] = MFMA_BF16(a_h[i], b_h, c2[i]);
                c2[i] = MFMA_BF16(a_l[i], b_h, c2[i]);
                c2[i] = MFMA_BF16(a_h[i], b_l, c2[i]);
            }
        }
        float* outp = ctxp + (((size_t)z * NHD + h) * 32 + tile) * 4096;
        #pragma unroll
        for (int i = 0; i < 2; ++i)
            #pragma unroll
            for (int r = 0; r < 4; ++r)
                outp[(size_t)(cr0 + i * 16 + kb * 4 + r) * 64 + cc0 + l15] = c2[i][r];
    } else {
        // ================= Q path (8-wave): m0 = (y-8)*128 =================
        const int m0 = (blockIdx.y - NHD) * 128;

        for (int k0 = 0; k0 < NC; k0 += 32) {
            {
                int idx = t;
                int m = idx & 127, s = idx >> 7;
                size_t goA = (size_t)(m0 + m) * NC + k0 + s * 8;
                size_t goB = (size_t)(n0 + m) * NC + k0 + s * 8;
                int lo = idx * 16;
                gload16(Wh + goA, smem + lo);
                gload16(Wl + goA, smem + 8192 + lo);
                gload16(Bh + goB, smem + 16384 + lo);
                gload16(Bl + goB, smem + 24576 + lo);
            }
            __syncthreads();
            bf16x8 ah[4], al[4];
            #pragma unroll
            for (int fi = 0; fi < 4; ++fi) {
                int off = (kb * 128 + wr * 64 + fi * 16 + l15) * 16;
                ah[fi] = *(const bf16x8*)(smem + off);
                al[fi] = *(const bf16x8*)(smem + 8192 + off);
            }
            #pragma unroll
            for (int fj = 0; fj < 2; ++fj) {
                int off = (kb * 128 + wc * 32 + fj * 16 + l15) * 16;
                bf16x8 bh = *(const bf16x8*)(smem + 16384 + off);
                bf16x8 bl = *(const bf16x8*)(smem + 24576 + off);
                #pragma unroll
                for (int fi = 0; fi < 4; ++fi) {
                    acc[fi][fj] = MFMA_BF16(ah[fi], bh, acc[fi][fj]);
                    acc[fi][fj] = MFMA_BF16(al[fi], bh, acc[fi][fj]);
                    acc[fi][fj] = MFMA_BF16(ah[fi], bl, acc[fi][fj]);
                }
            }
            __syncthreads();
        }

        // per-head feature softmax: wave-half wr covers one head (rows wr*64 + fi*16 + kb*4 + r)
        uint* Tq = (uint*)smem;    // [128 p][136], value = hb<<16 (aliases dead staging)
        #pragma unroll
        for (int fj = 0; fj < 2; ++fj) {
            float ex[16];
            float cs = 0.f;
            #pragma unroll
            for (int fi = 0; fi < 4; ++fi)
                #pragma unroll
                for (int r = 0; r < 4; ++r) {
                    float e = __expf(acc[fi][fj][r]);
                    ex[fi * 4 + r] = e;
                    cs += e;
                }
            cs += __shfl_xor(cs, 16);
            cs += __shfl_xor(cs, 32);
            float inv = 0.125f / cs;
            int p_loc = wc * 32 + fj * 16 + l15;
            #pragma unroll
            for (int fi = 0; fi < 4; ++fi)
                #pragma unroll
                for (int r = 0; r < 4; ++r) {
                    uint hb = bf16_rne(ex[fi * 4 + r] * inv);
                    Tq[p_loc * 136 + wr * 64 + fi * 16 + kb * 4 + r] = hb << 16;
                }
        }
        __syncthreads();
        int p = t >> 2, seg = t & 3;        // 128 p-rows x 4 segs of 32 hid
        size_t ob = ((size_t)z * NP + n0 + p) * HID + m0 + seg * 32;
        #pragma unroll
        for (int c = 0; c < 4; ++c) {
            uint4 H;
            uint* hp = (uint*)&H;
            #pragma unroll
            for (int i = 0; i < 4; ++i) {
                uint u0 = Tq[p * 136 + seg * 32 + c * 8 + 2 * i];
                uint u1 = Tq[p * 136 + seg * 32 + c * 8 + 2 * i + 1];
                hp[i] = (u0 >> 16) | (u1 & 0xffff0000u);
            }
            *(uint4*)(qsTh + ob + c * 8) = H;
        }
    }
}

// ===================== ksum reduce: 128 partials per (z,row) ==========
__global__ void ksum_reduce_kernel(const float* __restrict__ kspart,
                                   float* __restrict__ ksum, int n) {
    int i = blockIdx.x * 256 + threadIdx.x;
    if (i >= n) return;
    float s = 0.f;
    #pragma unroll
    for (int j = 0; j < 128; ++j) s += kspart[(size_t)i * 128 + j];
    ksum[i] = s;
}

// ===================== fold (+ctx reduce over 32 partials) ==========
__global__ __launch_bounds__(256) void fold_kernel(const float* __restrict__ out_w,
                                                   const float* __restrict__ ctxp,
                                                   const float* __restrict__ ksum,
                                                   ushort* __restrict__ w2h,
                                                   ushort* __restrict__ w2l) {
    int h = blockIdx.x, z = blockIdx.y;
    __shared__ float Cs[FD][FD];
    int t = threadIdx.x;
    const float* pbase = ctxp + ((size_t)z * NHD + h) * 32 * 4096;
    #pragma unroll
    for (int j = 0; j < 16; ++j) {
        int idx = t + j * 256;
        float s = 0.f;
        #pragma unroll
        for (int p8 = 0; p8 < 32; ++p8) s += pbase[(size_t)p8 * 4096 + idx];
        ((float*)Cs)[idx] = s;
    }
    __syncthreads();
    float wr[64];
    const float* wrow = out_w + (size_t)t * HID + h * FD;
    #pragma unroll
    for (int e = 0; e < 64; ++e) wr[e] = wrow[e];
    size_t ob = ((size_t)z * NC + t) * HID + h * FD;
    for (int f = 0; f < 64; ++f) {
        float sacc = 0.f;
        #pragma unroll
        for (int e = 0; e < 64; ++e) sacc = fmaf(wr[e], Cs[f][e], sacc);
        float v = sacc / ksum[(size_t)z * HID + h * FD + f];
        uint hb, lb;
        split2(v, hb, lb);
        w2h[ob + f] = (ushort)hb;
        w2l[ob + f] = (ushort)lb;
    }
}

// ===================== out GEMM (B = qsT hi-only) + bias + GN2 stats partials ==========
// grid (32, 2, CB), block 256
__global__ __launch_bounds__(256) void gemm_out_kernel(
        const ushort* __restrict__ Ahg, const ushort* __restrict__ Alg,
        const ushort* __restrict__ Bhg,
        const float* __restrict__ bias, float* __restrict__ outg,
        float2* __restrict__ gn2part, int b0) {
    __shared__ __align__(16) char smem[24576];
    const int z = blockIdx.z, bglob = b0 + z;
    const ushort* Ah = Ahg + (size_t)NC * HID * z;
    const ushort* Al = Alg + (size_t)NC * HID * z;
    const ushort* Bh = Bhg + (size_t)NP * HID * z;
    float* C = outg + (size_t)bglob * NC * NP;

    const int t = threadIdx.x;
    const int w = t >> 6, l = t & 63;
    const int wr = w >> 1, wc = w & 1;
    const int m0 = blockIdx.y * 128, n0 = blockIdx.x * 128;
    const int l15 = l & 15, kb = l >> 4;

    f32x4 acc[4][4];
    #pragma unroll
    for (int i = 0; i < 4; ++i)
        #pragma unroll
        for (int j = 0; j < 4; ++j)
            acc[i][j] = (f32x4){0.f, 0.f, 0.f, 0.f};

    for (int k0 = 0; k0 < HID; k0 += 32) {
        #pragma unroll
        for (int j = 0; j < 2; ++j) {
            int idx = t + j * 256;
            int m = idx & 127, s = idx >> 7;
            size_t goA = (size_t)(m0 + m) * HID + k0 + s * 8;
            size_t goB = (size_t)(n0 + m) * HID + k0 + s * 8;
            int lo = idx * 16;
            gload16(Ah + goA, smem + lo);
            gload16(Al + goA, smem + 8192 + lo);
            gload16(Bh + goB, smem + 16384 + lo);
        }
        __syncthreads();
        bf16x8 ah[4], al[4];
        #pragma unroll
        for (int fi = 0; fi < 4; ++fi) {
            int off = (kb * 128 + wr * 64 + fi * 16 + l15) * 16;
            ah[fi] = *(const bf16x8*)(smem + off);
            al[fi] = *(const bf16x8*)(smem + 8192 + off);
        }
        #pragma unroll
        for (int fj = 0; fj < 4; ++fj) {
            int off = (kb * 128 + wc * 64 + fj * 16 + l15) * 16;
            bf16x8 bh = *(const bf16x8*)(smem + 16384 + off);
            #pragma unroll
            for (int fi = 0; fi < 4; ++fi) {
                acc[fi][fj] = MFMA_BF16(ah[fi], bh, acc[fi][fj]);
                acc[fi][fj] = MFMA_BF16(al[fi], bh, acc[fi][fj]);
            }
        }
        __syncthreads();
    }

    float gs[4] = {0.f, 0.f, 0.f, 0.f}, gq[4] = {0.f, 0.f, 0.f, 0.f};
    #pragma unroll
    for (int fi = 0; fi < 4; ++fi) {
        int mbase = m0 + wr * 64 + fi * 16 + kb * 4;
        #pragma unroll
        for (int fj = 0; fj < 4; ++fj) {
            int n = n0 + wc * 64 + fj * 16 + l15;
            #pragma unroll
            for (int r = 0; r < 4; ++r) {
                float v = acc[fi][fj][r] + bias[mbase + r];
                C[(size_t)(mbase + r) * NP + n] = v;
                gs[fi] += v;
                gq[fi] += v * v;
            }
        }
    }
    #pragma unroll
    for (int fi = 0; fi < 4; ++fi) {
        #pragma unroll
        for (int d = 1; d <= 16; d <<= 1) {
            gs[fi] += __shfl_xor(gs[fi], d);
            gq[fi] += __shfl_xor(gq[fi], d);
        }
    }
    if (l15 == 0 && (kb & 1) == 0) {
        #pragma unroll
        for (int fi = 0; fi < 4; ++fi) {
            int g = ((m0 + wr * 64) >> 3) + fi * 2 + (kb >> 1);
            float2 pv; pv.x = gs[fi]; pv.y = gq[fi];
            gn2part[(((size_t)bglob * NG + g) << 6) + blockIdx.x * 2 + wc] = pv;
        }
    }
}

// ===================== GN2 partial reduce -> mu/rstd ==========
__global__ void gn2_reduce_kernel(const float2* __restrict__ gn2part,
                                  float* __restrict__ mu, float* __restrict__ rstd) {
    int i = blockIdx.x * 256 + threadIdx.x;   // NB*NG = 512
    if (i >= NB * NG) return;
    float s = 0.f, q = 0.f;
    #pragma unroll
    for (int j = 0; j < 64; ++j) {
        float2 p = gn2part[((size_t)i << 6) + j];
        s += p.x; q += p.y;
    }
    const float inv = 1.f / (float)(CPG * NP);
    float m = s * inv;
    float var = q * inv - m * m;
    mu[i] = m;
    rstd[i] = rsqrtf(var + GEPS);
}

// ===================== GN2 apply in-place on d_out =====================
__global__ void gn2_apply_kernel(float* __restrict__ out, const float* __restrict__ mu,
                                 const float* __restrict__ rstd, const float* __restrict__ w,
                                 const float* __restrict__ bias) {
    int i = blockIdx.x * 256 + threadIdx.x;
    float4* p = (float4*)out;
    float4 v = p[i];
    size_t e0 = (size_t)i * 4;
    int cidx = (int)((e0 / NP) % NC);
    int bg   = (int)(e0 / ((size_t)CPG * NP));
    float m = mu[bg], r = rstd[bg];
    float a = r * w[cidx];
    float d = bias[cidx] - m * a;
    v.x = fmaf(v.x, a, d); v.y = fmaf(v.y, a, d);
    v.z = fmaf(v.z, a, d); v.w = fmaf(v.w, a, d);
    p[i] = v;
}

// ===================== launch =====================
extern "C" void kernel_launch(void* const* d_in, const int* in_sizes, int n_in,
                              void* d_out, int out_size, void* d_ws, size_t ws_size,
                              hipStream_t stream) {
    const float* x     = (const float*)d_in[0];
    const float* gn1_w = (const float*)d_in[1];
    const float* gn1_b = (const float*)d_in[2];
    const float* qkv_w = (const float*)d_in[3];
    const float* out_w = (const float*)d_in[4];
    const float* out_b = (const float*)d_in[5];
    const float* gn2_w = (const float*)d_in[6];
    const float* gn2_b = (const float*)d_in[7];
    float* out = (float*)d_out;

    // ---- pick chunk size CB by workspace budget ----
    auto need = [](int cb) -> size_t {
        size_t tot = 0;
        auto al = [&](size_t b) { tot = (tot + b + 255) & ~(size_t)255; };
        al((size_t)cb * NP * NC * 2);  al((size_t)cb * NP * NC * 2);   // xT h/l
        al((size_t)cb * NP * HID * 2);                                 // qsT (hi only)
        al((size_t)cb * NHD * 32 * FD * FD * 4);                       // ctxp (32 tile partials)
        al((size_t)cb * HID * 128 * 4);                                // kspart
        al((size_t)cb * HID * 4);                                      // ksum
        al((size_t)cb * NC * HID * 2); al((size_t)cb * NC * HID * 2);  // w2 h/l
        al((size_t)OC3 * NC * 2); al((size_t)OC3 * NC * 2);            // Wq h/l
        al((size_t)2 * NB * NC * 4);                                   // ac,dc
        al((size_t)4 * NB * NG * 4);                                   // gn1/gn2 stats
        al((size_t)NB * NG * 64 * 8);                                  // gn2part float2
        return tot;
    };
    int CB = 1;
    {
        const int cands[5] = {16, 8, 4, 2, 1};
        for (int i = 0; i < 5; ++i) if (need(cands[i]) <= ws_size) { CB = cands[i]; break; }
    }

    // ---- carve workspace (same order as need()) ----
    char* base = (char*)d_ws;
    size_t off = 0;
    auto carve = [&](size_t b) -> char* {
        char* p = base + off;
        off = (off + b + 255) & ~(size_t)255;
        return p;
    };
    ushort* xTh  = (ushort*)carve((size_t)CB * NP * NC * 2);
    ushort* xTl  = (ushort*)carve((size_t)CB * NP * NC * 2);
    ushort* qsTh = (ushort*)carve((size_t)CB * NP * HID * 2);
    float*  ctxp = (float*) carve((size_t)CB * NHD * 32 * FD * FD * 4);
    float*  kspart = (float*)carve((size_t)CB * HID * 128 * 4);
    float*  ksum = (float*) carve((size_t)CB * HID * 4);
    ushort* w2h  = (ushort*)carve((size_t)CB * NC * HID * 2);
    ushort* w2l  = (ushort*)carve((size_t)CB * NC * HID * 2);
    ushort* Wqh  = (ushort*)carve((size_t)OC3 * NC * 2);
    ushort* Wql  = (ushort*)carve((size_t)OC3 * NC * 2);
    float*  ac   = (float*) carve((size_t)2 * NB * NC * 4);
    float*  dc   = ac + (size_t)NB * NC;
    float*  mu1  = (float*) carve((size_t)4 * NB * NG * 4);
    float*  rstd1 = mu1 + NB * NG;
    float*  mu2   = rstd1 + NB * NG;
    float*  rstd2 = mu2 + NB * NG;
    float2* gn2part = (float2*)carve((size_t)NB * NG * 64 * 8);

    // 1. GN1 stats + affine coefs + weight split
    gn_stats_kernel<<<NB * NG, 256, 0, stream>>>(x, mu1, rstd1);
    gn1_coefs_kernel<<<16, 256, 0, stream>>>(mu1, rstd1, gn1_w, gn1_b, ac, dc);
    wsplit_kernel<<<OC3 * NC / 1024, 256, 0, stream>>>(qkv_w, Wqh, Wql);

    // 2. chunked pipeline (KV-ctx and Q share one dispatch; qsT stays L3-hot for gemm_out)
    for (int b0 = 0; b0 < NB; b0 += CB) {
        xsplit_kernel<<<dim3(NP / 64, NC / 64, CB), 256, 0, stream>>>(x, ac, dc, xTh, xTl, b0);
        kvq_kernel<<<dim3(NP / 128, NHD + 4, CB), 512, 0, stream>>>(
            Wqh, Wql, xTh, xTl, ctxp, kspart, qsTh);
        ksum_reduce_kernel<<<(CB * HID + 255) / 256, 256, 0, stream>>>(kspart, ksum, CB * HID);
        fold_kernel<<<dim3(NHD, CB), 256, 0, stream>>>(out_w, ctxp, ksum, w2h, w2l);
        gemm_out_kernel<<<dim3(NP / 128, 2, CB), 256, 0, stream>>>(
            w2h, w2l, qsTh, out_b, out, gn2part, b0);
    }

    // 3. GN2 finalize
    gn2_reduce_kernel<<<2, 256, 0, stream>>>(gn2part, mu2, rstd2);
    gn2_apply_kernel<<<16384, 256, 0, stream>>>(out, mu2, rstd2, gn2_w, gn2_b);
}